// Round 1
// baseline (356.135 us; speedup 1.0000x reference)
//
#include <hip/hip_runtime.h>
#include <math.h>
#include <float.h>

// VideoQuantizer: rmsnorm -> per-subvector argmin over 4096 codewords -> gather -> rmsnorm
// B=8 T=1024 D=1024 Q=8 K=4096 d=128
// v2: fp16 2-pass distance (x split into fp16 hi+lo, codebook single RTN fp16 plane).
//     64 MFMA/wave/chunk (was 96 with bf16 3-pass); panels halve to 8MB; LDS 36KB.
#define Q_     8
#define K_     4096
#define dd_    128
#define D_     1024
#define ROWS   8192
#define NCHUNK 64
#define TAU    0.02f   // rescue threshold on d2/2 scale: fp16 b-round err ~6e-3 max + quant ~4e-3 < 0.02

typedef __attribute__((ext_vector_type(8))) _Float16 f16x8;
typedef __attribute__((ext_vector_type(4))) float f32x4;
typedef __attribute__((ext_vector_type(4))) unsigned int u32x4;

typedef const __attribute__((address_space(1))) unsigned int* gas_p;
typedef __attribute__((address_space(3))) unsigned int* las_p;

__device__ inline unsigned f2u(float x) { union { float f; unsigned u; } v; v.f = x; return v.u; }
__device__ inline float u2f(unsigned x) { union { unsigned u; float f; } v; v.u = x; return v.f; }
__device__ inline unsigned short f2h(float x) {
    union { _Float16 h; unsigned short u; } v; v.h = (_Float16)x; return v.u;
}
__device__ inline unsigned umin_(unsigned a, unsigned b) { return a < b ? a : b; }
__device__ inline unsigned umax_(unsigned a, unsigned b) { return a > b ? a : b; }

// ---------------- fused: panel build (negated fp16 plane) + c2/2 | input rmsnorm + x2/2 ----
// panels[q][c][n][slot][8 fp16] of NEGATED codewords; slot = j ^ (n&15)
__global__ void k_prep(const float* __restrict__ cb, const float* __restrict__ x,
                       const float* __restrict__ w, float* __restrict__ xn,
                       unsigned short* __restrict__ panels, float* __restrict__ c2h,
                       float* __restrict__ x2h, int* __restrict__ counter) {
    const int bid = blockIdx.x, t = threadIdx.x;
    if (bid == 0 && t == 0) *counter = 0;
    if (bid < NCHUNK * Q_) {
        // ---- panel prep ----
        int c = bid & 63, q = bid >> 6;
        const float* src = cb + ((size_t)q * K_ + c * 64) * dd_;
        unsigned short* dst = panels + (size_t)(q * NCHUNK + c) * 8192;
        #pragma unroll
        for (int i = 0; i < 4; i++) {
            int sid = i * 256 + t;
            int n = sid >> 4, j = sid & 15;
            const float* sp = src + n * dd_ + j * 8;
            f32x4 v0 = *(const f32x4*)sp;
            f32x4 v1 = *(const f32x4*)(sp + 4);
            float xs[8] = {v0.x, v0.y, v0.z, v0.w, v1.x, v1.y, v1.z, v1.w};
            unsigned short hb[8];
            float ss = 0.0f;
            #pragma unroll
            for (int e = 0; e < 8; e++) {
                float xv = -xs[e];                     // NEGATED codeword
                ss = fmaf(xv, xv, ss);
                hb[e] = f2h(xv);                       // single RTN fp16 plane
            }
            int slot = j ^ (n & 15);
            u32x4 H;
            H.x = (unsigned)hb[0] | ((unsigned)hb[1] << 16);
            H.y = (unsigned)hb[2] | ((unsigned)hb[3] << 16);
            H.z = (unsigned)hb[4] | ((unsigned)hb[5] << 16);
            H.w = (unsigned)hb[6] | ((unsigned)hb[7] << 16);
            *(u32x4*)&dst[(n * 16 + slot) * 8] = H;
            ss += __shfl_xor(ss, 1, 64);
            ss += __shfl_xor(ss, 2, 64);
            ss += __shfl_xor(ss, 4, 64);
            ss += __shfl_xor(ss, 8, 64);
            if (j == 0) c2h[q * K_ + c * 64 + n] = 0.5f * ss;   // exact f32 c2/2
        }
    } else {
        // ---- input rmsnorm + sub-vector x2/2 ----
        int row = bid - NCHUNK * Q_;
        const float4 v = *(const float4*)(x + (size_t)row * D_ + t * 4);
        float ss = v.x * v.x + v.y * v.y + v.z * v.z + v.w * v.w;
        #pragma unroll
        for (int o = 32; o > 0; o >>= 1) ss += __shfl_xor(ss, o, 64);
        __shared__ float acc[4];
        if ((t & 63) == 0) acc[t >> 6] = ss;
        __syncthreads();
        float tot = (acc[0] + acc[1]) + (acc[2] + acc[3]);
        float sc  = 1.0f / sqrtf(tot * (1.0f / D_) + 1e-5f);
        const float4 wv = *(const float4*)(w + t * 4);
        float4 o;
        o.x = v.x * sc * wv.x; o.y = v.y * sc * wv.y;
        o.z = v.z * sc * wv.z; o.w = v.w * sc * wv.w;
        *(float4*)(xn + (size_t)row * D_ + t * 4) = o;
        float so = o.x * o.x + o.y * o.y + o.z * o.z + o.w * o.w;
        so += __shfl_xor(so, 1, 64);
        so += __shfl_xor(so, 2, 64);
        so += __shfl_xor(so, 4, 64);
        so += __shfl_xor(so, 8, 64);
        so += __shfl_xor(so, 16, 64);
        if ((t & 31) == 0) x2h[row * Q_ + (t >> 5)] = 0.5f * so;
    }
}

// ---------------- 2-pass fp16 MFMA distance + packed-u32 top-2 argmin ----------------
// x split into fp16 hi+lo (~22 bits); B single fp16, negated. acc init = x2/2 + c2/2
// -> acc_final = d2/2 >= 0; pack (score&~0x7F)|tag, u32 mins. Near-ties -> rescue list.
__launch_bounds__(256, 2)
__global__ void k_dist(const float* __restrict__ xn, const unsigned short* __restrict__ panels,
                       const float* __restrict__ c2h, const float* __restrict__ x2h,
                       int* __restrict__ idxi, float* __restrict__ idxf,
                       int* __restrict__ list, int* __restrict__ counter) {
    __shared__ char smem[36864];   // 2 x 16KB staging; reduce scratch (33792B) overlaid after loop

    const int t    = threadIdx.x;
    const int lane = t & 63, wave = t >> 6;
    const int wm = wave >> 1, wn = wave & 1;
    const int col = lane & 15, quad = lane >> 4;
    const int q = blockIdx.y;
    const int row0 = blockIdx.x * 128;

    // A fragments (fp16 round-to-nearest split: x ~= hi + lo to ~22 bits)
    f16x8 ah[4][4], al[4][4];
    #pragma unroll
    for (int mt = 0; mt < 4; mt++) {
        #pragma unroll
        for (int kt = 0; kt < 4; kt++) {
            const float* ap = xn + (size_t)(row0 + wm * 64 + mt * 16 + col) * D_
                              + q * dd_ + kt * 32 + quad * 8;
            f32x4 v0 = *(const f32x4*)ap;
            f32x4 v1 = *(const f32x4*)(ap + 4);
            #pragma unroll
            for (int e = 0; e < 8; e++) {
                float xv = (e < 4) ? v0[e] : v1[e - 4];
                _Float16 h = (_Float16)xv;
                float r = xv - (float)h;
                ah[mt][kt][e] = h;
                al[mt][kt][e] = (_Float16)r;
            }
        }
    }

    // per-slot row halves of ||x_q||^2
    f32x4 x2v[4];
    #pragma unroll
    for (int mt = 0; mt < 4; mt++)
        #pragma unroll
        for (int r = 0; r < 4; r++)
            x2v[mt][r] = x2h[(size_t)(row0 + wm * 64 + mt * 16 + quad * 4 + r) * Q_ + q];

    unsigned m1[16], m2[16];
    #pragma unroll
    for (int i = 0; i < 16; i++) { m1[i] = 0xFFFFFFFFu; m2[i] = 0xFFFFFFFFu; }

    const size_t panq = (size_t)q * NCHUNK * 8192;
    const float* c2hq = c2h + q * K_;

    // preload chunk 0 staging (16KB: 4 x 4KB global_load_lds_dwordx4)
    {
        const unsigned short* src = panels + panq;
        #pragma unroll
        for (int i = 0; i < 4; i++) {
            int boff = i * 4096 + t * 16;
            __builtin_amdgcn_global_load_lds((gas_p)((const char*)src + boff),
                                             (las_p)(smem + boff), 16, 0, 0);
        }
    }
    float ch0 = c2hq[wn * 32 + col];
    float ch1 = c2hq[wn * 32 + col + 16];

    for (int c = 0; c < NCHUNK; c++) {
        __syncthreads();
        if (c + 1 < NCHUNK) {
            const unsigned short* src = panels + panq + (size_t)(c + 1) * 8192;
            char* stage = smem + ((c + 1) & 1) * 16384;
            #pragma unroll
            for (int i = 0; i < 4; i++) {
                int boff = i * 4096 + t * 16;
                __builtin_amdgcn_global_load_lds((gas_p)((const char*)src + boff),
                                                 (las_p)(stage + boff), 16, 0, 0);
            }
        }
        float ch0n = 0.0f, ch1n = 0.0f;
        if (c + 1 < NCHUNK) {
            ch0n = c2hq[(c + 1) * 64 + wn * 32 + col];
            ch1n = c2hq[(c + 1) * 64 + wn * 32 + col + 16];
        }
        const char* cbuf = smem + (c & 1) * 16384;

        f32x4 acc[4][2];
        #pragma unroll
        for (int mt = 0; mt < 4; mt++) {
            acc[mt][0] = x2v[mt] + ch0;   // d2/2 accumulator init
            acc[mt][1] = x2v[mt] + ch1;
        }

        #pragma unroll
        for (int kt = 0; kt < 4; kt++) {
            const int sw = ((quad + kt * 4) ^ col) * 16;
            const int a0 = (wn * 32 + col) * 256 + sw;        // codeword rows 0..15 of half 0
            const int a1 = a0 + 4096;                         // +16 rows (half 1)
            f16x8 b0 = *(const f16x8*)(cbuf + a0);
            f16x8 b1 = *(const f16x8*)(cbuf + a1);
            #pragma unroll
            for (int mt = 0; mt < 4; mt++) {
                acc[mt][0] = __builtin_amdgcn_mfma_f32_16x16x32_f16(ah[mt][kt], b0, acc[mt][0], 0, 0, 0);
                acc[mt][0] = __builtin_amdgcn_mfma_f32_16x16x32_f16(al[mt][kt], b0, acc[mt][0], 0, 0, 0);
                acc[mt][1] = __builtin_amdgcn_mfma_f32_16x16x32_f16(ah[mt][kt], b1, acc[mt][1], 0, 0, 0);
                acc[mt][1] = __builtin_amdgcn_mfma_f32_16x16x32_f16(al[mt][kt], b1, acc[mt][1], 0, 0, 0);
            }
        }

        const unsigned tg0 = (unsigned)(c << 1), tg1 = tg0 | 1u;
        #pragma unroll
        for (int mt = 0; mt < 4; mt++) {
            #pragma unroll
            for (int r = 0; r < 4; r++) {
                const int sl = mt * 4 + r;
                unsigned p0 = (f2u(acc[mt][0][r]) & 0xFFFFFF80u) | tg0;
                unsigned p1 = (f2u(acc[mt][1][r]) & 0xFFFFFF80u) | tg1;
                unsigned pmin = umin_(p0, p1), pmax = umax_(p0, p1);
                m2[sl] = umin_(umin_(m2[sl], umax_(m1[sl], pmin)), pmax);  // min3 fusion
                m1[sl] = umin_(m1[sl], pmin);
            }
        }
        ch0 = ch0n; ch1 = ch1n;
    }

    // cross-lane top-2 merge per row (u32 domain; stride 33)
    __syncthreads();
    unsigned* rm1 = (unsigned*)smem;             // [128][33]
    unsigned* rm2 = (unsigned*)(smem + 16896);
    #pragma unroll
    for (int mt = 0; mt < 4; mt++) {
        #pragma unroll
        for (int r = 0; r < 4; r++) {
            int sl = mt * 4 + r;
            int row_l = wm * 64 + mt * 16 + quad * 4 + r;
            int e = wn * 16 + col;
            rm1[row_l * 33 + e] = m1[sl];
            rm2[row_l * 33 + e] = m2[sl];
        }
    }
    __syncthreads();
    if (t < 128) {
        unsigned b1 = 0xFFFFFFFFu, b2 = 0xFFFFFFFFu;
        int be = 0;
        for (int e = 0; e < 32; e++) {
            unsigned v1 = rm1[t * 33 + e], v2 = rm2[t * 33 + e];
            b2 = umin_(b2, v2);
            if (v1 < b1) { b2 = umin_(b2, b1); b1 = v1; be = e; }
            else         { b2 = umin_(b2, v1); }
        }
        int tag = (int)(b1 & 0x7Fu);
        int k = ((tag >> 1) << 6) | ((be >> 4) << 5) | ((tag & 1) << 4) | (be & 15);
        float f1 = u2f(b1 & 0xFFFFFF80u);
        float f2 = u2f(b2 & 0xFFFFFF80u);
        int rg = row0 + t;
        idxi[rg * Q_ + q] = k;
        idxf[rg * Q_ + q] = (float)k;
        if (f2 - f1 < TAU) {                 // quantized ties -> gap 0 -> always rescued
            int p = atomicAdd(counter, 1);
            list[p] = rg * Q_ + q;
        }
    }
}

// ---------------- exact fp32 re-score of flagged (row,q) pairs (grid-stride, parallel) ----
__global__ void k_rescue(const float* __restrict__ xn, const float* __restrict__ cb,
                         const float* __restrict__ c2h, const int* __restrict__ list,
                         const int* __restrict__ counter, int* __restrict__ idxi,
                         float* __restrict__ idxf) {
    __shared__ float xq[dd_];
    __shared__ float bs_sh[256];
    __shared__ int   bk_sh[256];
    const int n = *counter;
    const int t = threadIdx.x;
    for (int it = blockIdx.x; it < n; it += gridDim.x) {
        __syncthreads();
        int item = list[it];
        int rg = item >> 3, q = item & 7;
        if (t < dd_) xq[t] = xn[(size_t)rg * D_ + q * dd_ + t];
        __syncthreads();
        float bs = FLT_MAX; int bk = 0x7fffffff;
        for (int i = 0; i < 16; i++) {
            int k = i * 256 + t;
            const float* cp = cb + ((size_t)q * K_ + k) * dd_;
            float dot = 0.0f;
            #pragma unroll 8
            for (int d = 0; d < dd_; d += 4) {
                f32x4 cv = *(const f32x4*)(cp + d);
                dot = fmaf(cv.x, xq[d],     dot);
                dot = fmaf(cv.y, xq[d + 1], dot);
                dot = fmaf(cv.z, xq[d + 2], dot);
                dot = fmaf(cv.w, xq[d + 3], dot);
            }
            float s = c2h[q * K_ + k] - dot;   // d2/2 - x2/2 (monotone in d2)
            if (s < bs || (s == bs && k < bk)) { bs = s; bk = k; }
        }
        bs_sh[t] = bs; bk_sh[t] = bk;
        __syncthreads();
        if (t == 0) {
            float B = FLT_MAX; int K2 = 0x7fffffff;
            for (int e = 0; e < 256; e++) {
                if (bs_sh[e] < B || (bs_sh[e] == B && bk_sh[e] < K2)) { B = bs_sh[e]; K2 = bk_sh[e]; }
            }
            idxi[item] = K2;
            idxf[item] = (float)K2;
        }
    }
}

// ---------------- gather + output rmsnorm ----------------
__global__ void k_out(const float* __restrict__ cb, const int* __restrict__ idx_i,
                      const float* __restrict__ w, float* __restrict__ out) {
    int row = blockIdx.x;
    int t   = threadIdx.x;
    __shared__ int   sidx[Q_];
    __shared__ float acc[4];
    if (t < Q_) sidx[t] = idx_i[row * Q_ + t];
    __syncthreads();
    int col = t * 4;
    int q   = col >> 7;
    int dc  = col & 127;
    const float4 v = *(const float4*)(cb + ((size_t)q * K_ + sidx[q]) * dd_ + dc);
    float ss = v.x * v.x + v.y * v.y + v.z * v.z + v.w * v.w;
    #pragma unroll
    for (int o = 32; o > 0; o >>= 1) ss += __shfl_xor(ss, o, 64);
    if ((t & 63) == 0) acc[t >> 6] = ss;
    __syncthreads();
    float tot = (acc[0] + acc[1]) + (acc[2] + acc[3]);
    float sc  = 1.0f / sqrtf(tot * (1.0f / D_) + 1e-5f);
    const float4 wv = *(const float4*)(w + col);
    float4 o;
    o.x = v.x * sc * wv.x; o.y = v.y * sc * wv.y;
    o.z = v.z * sc * wv.z; o.w = v.w * sc * wv.w;
    *(float4*)(out + (size_t)row * D_ + col) = o;
}

extern "C" void kernel_launch(void* const* d_in, const int* in_sizes, int n_in,
                              void* d_out, int out_size, void* d_ws, size_t ws_size,
                              hipStream_t stream) {
    const float* x     = (const float*)d_in[0];
    const float* cb    = (const float*)d_in[1];
    const float* w_in  = (const float*)d_in[2];
    const float* w_out = (const float*)d_in[3];

    float* out  = (float*)d_out;                  // xn lives here between k_prep and k_out
    float* idxf = out + (size_t)ROWS * D_;

    // ws: panels 8MB | c2h 128KB | x2h 256KB | idxi 256KB | list 256KB | counter
    unsigned short* panels = (unsigned short*)d_ws;
    float* c2h  = (float*)((char*)d_ws + (8u << 20));
    float* x2h  = c2h + Q_ * K_;
    int*   idxi = (int*)(x2h + (size_t)ROWS * Q_);
    int*   list = idxi + ROWS * Q_;
    int*   counter = list + ROWS * Q_;

    k_prep  <<<dim3(NCHUNK * Q_ + ROWS), 256, 0, stream>>>(cb, x, w_in, out, panels, c2h, x2h, counter);
    k_dist  <<<dim3(ROWS / 128, Q_),     256, 0, stream>>>(out, panels, c2h, x2h, idxi, idxf, list, counter);
    k_rescue<<<dim3(1024),               256, 0, stream>>>(out, cb, c2h, list, counter, idxi, idxf);
    k_out   <<<dim3(ROWS),               256, 0, stream>>>(cb, idxi, w_out, out);
}

// Round 2
// 293.842 us; speedup vs baseline: 1.2120x; 1.2120x over previous
//
#include <hip/hip_runtime.h>
#include <math.h>
#include <float.h>

// VideoQuantizer: rmsnorm -> per-subvector argmin over 4096 codewords -> gather -> rmsnorm
// B=8 T=1024 D=1024 Q=8 K=4096 d=128
// v3: fp16 2-pass distance (unchanged) + parallel rescue:
//     8 blocks/item x 512 codewords, packed u64 atomicMin merge, k_fin decode.
//     TAU 0.02 -> 0.012 (fp16 err max ~4e-3 + 2x quant 2e-3 -> needed ~6e-3, 2x margin).
#define Q_     8
#define K_     4096
#define dd_    128
#define D_     1024
#define ROWS   8192
#define NCHUNK 64
#define TAU    0.012f

typedef __attribute__((ext_vector_type(8))) _Float16 f16x8;
typedef __attribute__((ext_vector_type(4))) float f32x4;
typedef __attribute__((ext_vector_type(4))) unsigned int u32x4;

typedef const __attribute__((address_space(1))) unsigned int* gas_p;
typedef __attribute__((address_space(3))) unsigned int* las_p;

__device__ inline unsigned f2u(float x) { union { float f; unsigned u; } v; v.f = x; return v.u; }
__device__ inline float u2f(unsigned x) { union { unsigned u; float f; } v; v.u = x; return v.f; }
__device__ inline unsigned short f2h(float x) {
    union { _Float16 h; unsigned short u; } v; v.h = (_Float16)x; return v.u;
}
__device__ inline unsigned umin_(unsigned a, unsigned b) { return a < b ? a : b; }
__device__ inline unsigned umax_(unsigned a, unsigned b) { return a > b ? a : b; }
// order-preserving f32 -> u32 (total order; smaller float -> smaller uint)
__device__ inline unsigned fflip(float x) {
    unsigned u = f2u(x);
    return (u & 0x80000000u) ? ~u : (u | 0x80000000u);
}
__device__ inline unsigned long long shfl_xor_u64(unsigned long long v, int m) {
    unsigned lo = (unsigned)v, hi = (unsigned)(v >> 32);
    lo = __shfl_xor(lo, m, 64);
    hi = __shfl_xor(hi, m, 64);
    return ((unsigned long long)hi << 32) | lo;
}

// ---------------- fused: panel build (negated fp16 plane) + c2/2 | input rmsnorm + x2/2 ----
// panels[q][c][n][slot][8 fp16] of NEGATED codewords; slot = j ^ (n&15)
__global__ void k_prep(const float* __restrict__ cb, const float* __restrict__ x,
                       const float* __restrict__ w, float* __restrict__ xn,
                       unsigned short* __restrict__ panels, float* __restrict__ c2h,
                       float* __restrict__ x2h, int* __restrict__ counter) {
    const int bid = blockIdx.x, t = threadIdx.x;
    if (bid == 0 && t == 0) *counter = 0;
    if (bid < NCHUNK * Q_) {
        // ---- panel prep ----
        int c = bid & 63, q = bid >> 6;
        const float* src = cb + ((size_t)q * K_ + c * 64) * dd_;
        unsigned short* dst = panels + (size_t)(q * NCHUNK + c) * 8192;
        #pragma unroll
        for (int i = 0; i < 4; i++) {
            int sid = i * 256 + t;
            int n = sid >> 4, j = sid & 15;
            const float* sp = src + n * dd_ + j * 8;
            f32x4 v0 = *(const f32x4*)sp;
            f32x4 v1 = *(const f32x4*)(sp + 4);
            float xs[8] = {v0.x, v0.y, v0.z, v0.w, v1.x, v1.y, v1.z, v1.w};
            unsigned short hb[8];
            float ss = 0.0f;
            #pragma unroll
            for (int e = 0; e < 8; e++) {
                float xv = -xs[e];                     // NEGATED codeword
                ss = fmaf(xv, xv, ss);
                hb[e] = f2h(xv);                       // single RTN fp16 plane
            }
            int slot = j ^ (n & 15);
            u32x4 H;
            H.x = (unsigned)hb[0] | ((unsigned)hb[1] << 16);
            H.y = (unsigned)hb[2] | ((unsigned)hb[3] << 16);
            H.z = (unsigned)hb[4] | ((unsigned)hb[5] << 16);
            H.w = (unsigned)hb[6] | ((unsigned)hb[7] << 16);
            *(u32x4*)&dst[(n * 16 + slot) * 8] = H;
            ss += __shfl_xor(ss, 1, 64);
            ss += __shfl_xor(ss, 2, 64);
            ss += __shfl_xor(ss, 4, 64);
            ss += __shfl_xor(ss, 8, 64);
            if (j == 0) c2h[q * K_ + c * 64 + n] = 0.5f * ss;   // exact f32 c2/2
        }
    } else {
        // ---- input rmsnorm + sub-vector x2/2 ----
        int row = bid - NCHUNK * Q_;
        const float4 v = *(const float4*)(x + (size_t)row * D_ + t * 4);
        float ss = v.x * v.x + v.y * v.y + v.z * v.z + v.w * v.w;
        #pragma unroll
        for (int o = 32; o > 0; o >>= 1) ss += __shfl_xor(ss, o, 64);
        __shared__ float acc[4];
        if ((t & 63) == 0) acc[t >> 6] = ss;
        __syncthreads();
        float tot = (acc[0] + acc[1]) + (acc[2] + acc[3]);
        float sc  = 1.0f / sqrtf(tot * (1.0f / D_) + 1e-5f);
        const float4 wv = *(const float4*)(w + t * 4);
        float4 o;
        o.x = v.x * sc * wv.x; o.y = v.y * sc * wv.y;
        o.z = v.z * sc * wv.z; o.w = v.w * sc * wv.w;
        *(float4*)(xn + (size_t)row * D_ + t * 4) = o;
        float so = o.x * o.x + o.y * o.y + o.z * o.z + o.w * o.w;
        so += __shfl_xor(so, 1, 64);
        so += __shfl_xor(so, 2, 64);
        so += __shfl_xor(so, 4, 64);
        so += __shfl_xor(so, 8, 64);
        so += __shfl_xor(so, 16, 64);
        if ((t & 31) == 0) x2h[row * Q_ + (t >> 5)] = 0.5f * so;
    }
}

// ---------------- 2-pass fp16 MFMA distance + packed-u32 top-2 argmin ----------------
// x split into fp16 hi+lo (~22 bits); B single fp16, negated. acc init = x2/2 + c2/2
// -> acc_final = d2/2 >= 0; pack (score&~0x7F)|tag, u32 mins. Near-ties -> rescue list.
__launch_bounds__(256, 2)
__global__ void k_dist(const float* __restrict__ xn, const unsigned short* __restrict__ panels,
                       const float* __restrict__ c2h, const float* __restrict__ x2h,
                       int* __restrict__ idxi, float* __restrict__ idxf,
                       int* __restrict__ list, int* __restrict__ counter,
                       unsigned long long* __restrict__ resc) {
    __shared__ char smem[36864];   // 2 x 16KB staging; reduce scratch (33792B) overlaid after loop

    const int t    = threadIdx.x;
    const int lane = t & 63, wave = t >> 6;
    const int wm = wave >> 1, wn = wave & 1;
    const int col = lane & 15, quad = lane >> 4;
    const int q = blockIdx.y;
    const int row0 = blockIdx.x * 128;

    // A fragments (fp16 round-to-nearest split: x ~= hi + lo to ~22 bits)
    f16x8 ah[4][4], al[4][4];
    #pragma unroll
    for (int mt = 0; mt < 4; mt++) {
        #pragma unroll
        for (int kt = 0; kt < 4; kt++) {
            const float* ap = xn + (size_t)(row0 + wm * 64 + mt * 16 + col) * D_
                              + q * dd_ + kt * 32 + quad * 8;
            f32x4 v0 = *(const f32x4*)ap;
            f32x4 v1 = *(const f32x4*)(ap + 4);
            #pragma unroll
            for (int e = 0; e < 8; e++) {
                float xv = (e < 4) ? v0[e] : v1[e - 4];
                _Float16 h = (_Float16)xv;
                float r = xv - (float)h;
                ah[mt][kt][e] = h;
                al[mt][kt][e] = (_Float16)r;
            }
        }
    }

    // per-slot row halves of ||x_q||^2
    f32x4 x2v[4];
    #pragma unroll
    for (int mt = 0; mt < 4; mt++)
        #pragma unroll
        for (int r = 0; r < 4; r++)
            x2v[mt][r] = x2h[(size_t)(row0 + wm * 64 + mt * 16 + quad * 4 + r) * Q_ + q];

    unsigned m1[16], m2[16];
    #pragma unroll
    for (int i = 0; i < 16; i++) { m1[i] = 0xFFFFFFFFu; m2[i] = 0xFFFFFFFFu; }

    const size_t panq = (size_t)q * NCHUNK * 8192;
    const float* c2hq = c2h + q * K_;

    // preload chunk 0 staging (16KB: 4 x 4KB global_load_lds_dwordx4)
    {
        const unsigned short* src = panels + panq;
        #pragma unroll
        for (int i = 0; i < 4; i++) {
            int boff = i * 4096 + t * 16;
            __builtin_amdgcn_global_load_lds((gas_p)((const char*)src + boff),
                                             (las_p)(smem + boff), 16, 0, 0);
        }
    }
    float ch0 = c2hq[wn * 32 + col];
    float ch1 = c2hq[wn * 32 + col + 16];

    for (int c = 0; c < NCHUNK; c++) {
        __syncthreads();
        if (c + 1 < NCHUNK) {
            const unsigned short* src = panels + panq + (size_t)(c + 1) * 8192;
            char* stage = smem + ((c + 1) & 1) * 16384;
            #pragma unroll
            for (int i = 0; i < 4; i++) {
                int boff = i * 4096 + t * 16;
                __builtin_amdgcn_global_load_lds((gas_p)((const char*)src + boff),
                                                 (las_p)(stage + boff), 16, 0, 0);
            }
        }
        float ch0n = 0.0f, ch1n = 0.0f;
        if (c + 1 < NCHUNK) {
            ch0n = c2hq[(c + 1) * 64 + wn * 32 + col];
            ch1n = c2hq[(c + 1) * 64 + wn * 32 + col + 16];
        }
        const char* cbuf = smem + (c & 1) * 16384;

        f32x4 acc[4][2];
        #pragma unroll
        for (int mt = 0; mt < 4; mt++) {
            acc[mt][0] = x2v[mt] + ch0;   // d2/2 accumulator init
            acc[mt][1] = x2v[mt] + ch1;
        }

        #pragma unroll
        for (int kt = 0; kt < 4; kt++) {
            const int sw = ((quad + kt * 4) ^ col) * 16;
            const int a0 = (wn * 32 + col) * 256 + sw;        // codeword rows 0..15 of half 0
            const int a1 = a0 + 4096;                         // +16 rows (half 1)
            f16x8 b0 = *(const f16x8*)(cbuf + a0);
            f16x8 b1 = *(const f16x8*)(cbuf + a1);
            #pragma unroll
            for (int mt = 0; mt < 4; mt++) {
                acc[mt][0] = __builtin_amdgcn_mfma_f32_16x16x32_f16(ah[mt][kt], b0, acc[mt][0], 0, 0, 0);
                acc[mt][0] = __builtin_amdgcn_mfma_f32_16x16x32_f16(al[mt][kt], b0, acc[mt][0], 0, 0, 0);
                acc[mt][1] = __builtin_amdgcn_mfma_f32_16x16x32_f16(ah[mt][kt], b1, acc[mt][1], 0, 0, 0);
                acc[mt][1] = __builtin_amdgcn_mfma_f32_16x16x32_f16(al[mt][kt], b1, acc[mt][1], 0, 0, 0);
            }
        }

        const unsigned tg0 = (unsigned)(c << 1), tg1 = tg0 | 1u;
        #pragma unroll
        for (int mt = 0; mt < 4; mt++) {
            #pragma unroll
            for (int r = 0; r < 4; r++) {
                const int sl = mt * 4 + r;
                unsigned p0 = (f2u(acc[mt][0][r]) & 0xFFFFFF80u) | tg0;
                unsigned p1 = (f2u(acc[mt][1][r]) & 0xFFFFFF80u) | tg1;
                unsigned pmin = umin_(p0, p1), pmax = umax_(p0, p1);
                m2[sl] = umin_(umin_(m2[sl], umax_(m1[sl], pmin)), pmax);  // min3 fusion
                m1[sl] = umin_(m1[sl], pmin);
            }
        }
        ch0 = ch0n; ch1 = ch1n;
    }

    // cross-lane top-2 merge per row (u32 domain; stride 33)
    __syncthreads();
    unsigned* rm1 = (unsigned*)smem;             // [128][33]
    unsigned* rm2 = (unsigned*)(smem + 16896);
    #pragma unroll
    for (int mt = 0; mt < 4; mt++) {
        #pragma unroll
        for (int r = 0; r < 4; r++) {
            int sl = mt * 4 + r;
            int row_l = wm * 64 + mt * 16 + quad * 4 + r;
            int e = wn * 16 + col;
            rm1[row_l * 33 + e] = m1[sl];
            rm2[row_l * 33 + e] = m2[sl];
        }
    }
    __syncthreads();
    if (t < 128) {
        unsigned b1 = 0xFFFFFFFFu, b2 = 0xFFFFFFFFu;
        int be = 0;
        for (int e = 0; e < 32; e++) {
            unsigned v1 = rm1[t * 33 + e], v2 = rm2[t * 33 + e];
            b2 = umin_(b2, v2);
            if (v1 < b1) { b2 = umin_(b2, b1); b1 = v1; be = e; }
            else         { b2 = umin_(b2, v1); }
        }
        int tag = (int)(b1 & 0x7Fu);
        int k = ((tag >> 1) << 6) | ((be >> 4) << 5) | ((tag & 1) << 4) | (be & 15);
        float f1 = u2f(b1 & 0xFFFFFF80u);
        float f2 = u2f(b2 & 0xFFFFFF80u);
        int rg = row0 + t;
        idxi[rg * Q_ + q] = k;
        idxf[rg * Q_ + q] = (float)k;
        if (f2 - f1 < TAU) {                 // quantized ties -> gap 0 -> always rescued
            int item = rg * Q_ + q;
            resc[item] = 0xFFFFFFFFFFFFFFFFull;   // init atomicMin slot
            int p = atomicAdd(counter, 1);
            list[p] = item;
        }
    }
}

// ---------------- exact fp32 re-score of flagged (row,q) pairs ----------------
// 8 blocks per item, 512 codewords each; merge via packed u64 atomicMin
// (flipped score high, k low -> smallest score, ties to smallest k).
__global__ void k_rescue(const float* __restrict__ xn, const float* __restrict__ cb,
                         const float* __restrict__ c2h, const int* __restrict__ list,
                         const int* __restrict__ counter,
                         unsigned long long* __restrict__ resc) {
    __shared__ float xq[dd_];
    __shared__ unsigned long long wbest[4];
    const int n = *counter;
    const int t = threadIdx.x;
    const int seg = blockIdx.x & 7;
    const int istep = gridDim.x >> 3;
    for (int ii = blockIdx.x >> 3; ii < n; ii += istep) {
        __syncthreads();
        int item = list[ii];
        int rg = item >> 3, q = item & 7;
        if (t < dd_) xq[t] = xn[(size_t)rg * D_ + q * dd_ + t];
        __syncthreads();
        unsigned long long best = 0xFFFFFFFFFFFFFFFFull;
        #pragma unroll
        for (int i = 0; i < 2; i++) {
            int k = seg * 512 + i * 256 + t;
            const float* cp = cb + ((size_t)q * K_ + k) * dd_;
            float dot = 0.0f;
            #pragma unroll 8
            for (int d = 0; d < dd_; d += 4) {
                f32x4 cv = *(const f32x4*)(cp + d);
                dot = fmaf(cv.x, xq[d],     dot);
                dot = fmaf(cv.y, xq[d + 1], dot);
                dot = fmaf(cv.z, xq[d + 2], dot);
                dot = fmaf(cv.w, xq[d + 3], dot);
            }
            float s = c2h[q * K_ + k] - dot;   // d2/2 - x2/2 (monotone in d2)
            unsigned long long key = ((unsigned long long)fflip(s) << 32) | (unsigned)k;
            best = best < key ? best : key;
        }
        // wave tree-reduce (u64 min), then cross-wave via LDS, then atomicMin
        #pragma unroll
        for (int o = 32; o > 0; o >>= 1) {
            unsigned long long other = shfl_xor_u64(best, o);
            best = best < other ? best : other;
        }
        if ((t & 63) == 0) wbest[t >> 6] = best;
        __syncthreads();
        if (t == 0) {
            unsigned long long b = wbest[0];
            b = b < wbest[1] ? b : wbest[1];
            b = b < wbest[2] ? b : wbest[2];
            b = b < wbest[3] ? b : wbest[3];
            atomicMin(&resc[item], b);
        }
    }
}

// ---------------- decode rescue winners into idxi/idxf ----------------
__global__ void k_fin(const int* __restrict__ list, const int* __restrict__ counter,
                      const unsigned long long* __restrict__ resc,
                      int* __restrict__ idxi, float* __restrict__ idxf) {
    const int n = *counter;
    for (int i = blockIdx.x * blockDim.x + threadIdx.x; i < n; i += gridDim.x * blockDim.x) {
        int item = list[i];
        int k = (int)(unsigned)(resc[item] & 0xFFFFFFFFull);
        idxi[item] = k;
        idxf[item] = (float)k;
    }
}

// ---------------- gather + output rmsnorm ----------------
__global__ void k_out(const float* __restrict__ cb, const int* __restrict__ idx_i,
                      const float* __restrict__ w, float* __restrict__ out) {
    int row = blockIdx.x;
    int t   = threadIdx.x;
    __shared__ int   sidx[Q_];
    __shared__ float acc[4];
    if (t < Q_) sidx[t] = idx_i[row * Q_ + t];
    __syncthreads();
    int col = t * 4;
    int q   = col >> 7;
    int dc  = col & 127;
    const float4 v = *(const float4*)(cb + ((size_t)q * K_ + sidx[q]) * dd_ + dc);
    float ss = v.x * v.x + v.y * v.y + v.z * v.z + v.w * v.w;
    #pragma unroll
    for (int o = 32; o > 0; o >>= 1) ss += __shfl_xor(ss, o, 64);
    if ((t & 63) == 0) acc[t >> 6] = ss;
    __syncthreads();
    float tot = (acc[0] + acc[1]) + (acc[2] + acc[3]);
    float sc  = 1.0f / sqrtf(tot * (1.0f / D_) + 1e-5f);
    const float4 wv = *(const float4*)(w + col);
    float4 o;
    o.x = v.x * sc * wv.x; o.y = v.y * sc * wv.y;
    o.z = v.z * sc * wv.z; o.w = v.w * sc * wv.w;
    *(float4*)(out + (size_t)row * D_ + col) = o;
}

extern "C" void kernel_launch(void* const* d_in, const int* in_sizes, int n_in,
                              void* d_out, int out_size, void* d_ws, size_t ws_size,
                              hipStream_t stream) {
    const float* x     = (const float*)d_in[0];
    const float* cb    = (const float*)d_in[1];
    const float* w_in  = (const float*)d_in[2];
    const float* w_out = (const float*)d_in[3];

    float* out  = (float*)d_out;                  // xn lives here between k_prep and k_out
    float* idxf = out + (size_t)ROWS * D_;

    // ws: panels 8MB | c2h 128KB | x2h 256KB | resc 512KB (u64) | idxi 256KB | list 256KB | counter
    unsigned short* panels = (unsigned short*)d_ws;
    float* c2h  = (float*)((char*)d_ws + (8u << 20));
    float* x2h  = c2h + Q_ * K_;
    unsigned long long* resc = (unsigned long long*)(x2h + (size_t)ROWS * Q_);
    int*   idxi = (int*)(resc + (size_t)ROWS * Q_);
    int*   list = idxi + ROWS * Q_;
    int*   counter = list + ROWS * Q_;

    k_prep  <<<dim3(NCHUNK * Q_ + ROWS), 256, 0, stream>>>(cb, x, w_in, out, panels, c2h, x2h, counter);
    k_dist  <<<dim3(ROWS / 128, Q_),     256, 0, stream>>>(out, panels, c2h, x2h, idxi, idxf, list, counter, resc);
    k_rescue<<<dim3(4096),               256, 0, stream>>>(out, cb, c2h, list, counter, resc);
    k_fin   <<<dim3(64),                 256, 0, stream>>>(list, counter, resc, idxi, idxf);
    k_out   <<<dim3(ROWS),               256, 0, stream>>>(cb, idxi, w_out, out);
}

// Round 3
// 246.656 us; speedup vs baseline: 1.4439x; 1.1913x over previous
//
#include <hip/hip_runtime.h>
#include <math.h>
#include <float.h>

// VideoQuantizer: rmsnorm -> per-subvector argmin over 4096 codewords -> gather -> rmsnorm
// B=8 T=1024 D=1024 Q=8 K=4096 d=128
// v4: z-split k_dist (2 K-halves, 1024 blocks -> 4 blocks/CU for MFMA/VALU overlap)
//     + shortlist rescue: per-z records carry <=2 rival (score,k) pairs from the
//     cross-lane merge; exact re-score of <=6 candidates (2KB) replaces the 2MB full
//     scan; full scan only when a lane's m2 is within TAU (hidden-3rd, ~n/32 items).
#define Q_     8
#define K_     4096
#define dd_    128
#define D_     1024
#define ROWS   8192
#define NCHUNK 64
#define NCH_L  32      // chunks per z-half
#define TAU    0.02f   // rescue band on d2/2 scale (fp16-b err + 7-bit quant << 0.02)

typedef __attribute__((ext_vector_type(8))) _Float16 f16x8;
typedef __attribute__((ext_vector_type(4))) float f32x4;
typedef __attribute__((ext_vector_type(4))) unsigned int u32x4;

typedef const __attribute__((address_space(1))) unsigned int* gas_p;
typedef __attribute__((address_space(3))) unsigned int* las_p;

__device__ inline unsigned f2u(float x) { union { float f; unsigned u; } v; v.f = x; return v.u; }
__device__ inline float u2f(unsigned x) { union { unsigned u; float f; } v; v.u = x; return v.f; }
__device__ inline unsigned short f2h(float x) {
    union { _Float16 h; unsigned short u; } v; v.h = (_Float16)x; return v.u;
}
__device__ inline unsigned umin_(unsigned a, unsigned b) { return a < b ? a : b; }
__device__ inline unsigned umax_(unsigned a, unsigned b) { return a > b ? a : b; }
// order-preserving f32 -> u32 (total order; smaller float -> smaller uint)
__device__ inline unsigned fflip(float x) {
    unsigned u = f2u(x);
    return (u & 0x80000000u) ? ~u : (u | 0x80000000u);
}
__device__ inline unsigned long long shfl_xor_u64(unsigned long long v, int m) {
    unsigned lo = (unsigned)v, hi = (unsigned)(v >> 32);
    lo = __shfl_xor(lo, m, 64);
    hi = __shfl_xor(hi, m, 64);
    return ((unsigned long long)hi << 32) | lo;
}

// ---------------- fused: panel build (negated fp16 plane) + c2/2 | input rmsnorm + x2/2 ----
// panels[q][c][n][slot][8 fp16] of NEGATED codewords; slot = j ^ (n&15)
__global__ void k_prep(const float* __restrict__ cb, const float* __restrict__ x,
                       const float* __restrict__ w, float* __restrict__ xn,
                       unsigned short* __restrict__ panels, float* __restrict__ c2h,
                       float* __restrict__ x2h, int* __restrict__ cntF, int* __restrict__ cntS) {
    const int bid = blockIdx.x, t = threadIdx.x;
    if (bid == 0 && t == 0) { *cntF = 0; *cntS = 0; }
    if (bid < NCHUNK * Q_) {
        // ---- panel prep ----
        int c = bid & 63, q = bid >> 6;
        const float* src = cb + ((size_t)q * K_ + c * 64) * dd_;
        unsigned short* dst = panels + (size_t)(q * NCHUNK + c) * 8192;
        #pragma unroll
        for (int i = 0; i < 4; i++) {
            int sid = i * 256 + t;
            int n = sid >> 4, j = sid & 15;
            const float* sp = src + n * dd_ + j * 8;
            f32x4 v0 = *(const f32x4*)sp;
            f32x4 v1 = *(const f32x4*)(sp + 4);
            float xs[8] = {v0.x, v0.y, v0.z, v0.w, v1.x, v1.y, v1.z, v1.w};
            unsigned short hb[8];
            float ss = 0.0f;
            #pragma unroll
            for (int e = 0; e < 8; e++) {
                float xv = -xs[e];                     // NEGATED codeword
                ss = fmaf(xv, xv, ss);
                hb[e] = f2h(xv);                       // single RTN fp16 plane
            }
            int slot = j ^ (n & 15);
            u32x4 H;
            H.x = (unsigned)hb[0] | ((unsigned)hb[1] << 16);
            H.y = (unsigned)hb[2] | ((unsigned)hb[3] << 16);
            H.z = (unsigned)hb[4] | ((unsigned)hb[5] << 16);
            H.w = (unsigned)hb[6] | ((unsigned)hb[7] << 16);
            *(u32x4*)&dst[(n * 16 + slot) * 8] = H;
            ss += __shfl_xor(ss, 1, 64);
            ss += __shfl_xor(ss, 2, 64);
            ss += __shfl_xor(ss, 4, 64);
            ss += __shfl_xor(ss, 8, 64);
            if (j == 0) c2h[q * K_ + c * 64 + n] = 0.5f * ss;   // exact f32 c2/2
        }
    } else {
        // ---- input rmsnorm + sub-vector x2/2 ----
        int row = bid - NCHUNK * Q_;
        const float4 v = *(const float4*)(x + (size_t)row * D_ + t * 4);
        float ss = v.x * v.x + v.y * v.y + v.z * v.z + v.w * v.w;
        #pragma unroll
        for (int o = 32; o > 0; o >>= 1) ss += __shfl_xor(ss, o, 64);
        __shared__ float acc[4];
        if ((t & 63) == 0) acc[t >> 6] = ss;
        __syncthreads();
        float tot = (acc[0] + acc[1]) + (acc[2] + acc[3]);
        float sc  = 1.0f / sqrtf(tot * (1.0f / D_) + 1e-5f);
        const float4 wv = *(const float4*)(w + t * 4);
        float4 o;
        o.x = v.x * sc * wv.x; o.y = v.y * sc * wv.y;
        o.z = v.z * sc * wv.z; o.w = v.w * sc * wv.w;
        *(float4*)(xn + (size_t)row * D_ + t * 4) = o;
        float so = o.x * o.x + o.y * o.y + o.z * o.z + o.w * o.w;
        so += __shfl_xor(so, 1, 64);
        so += __shfl_xor(so, 2, 64);
        so += __shfl_xor(so, 4, 64);
        so += __shfl_xor(so, 8, 64);
        so += __shfl_xor(so, 16, 64);
        if ((t & 31) == 0) x2h[row * Q_ + (t >> 5)] = 0.5f * so;
    }
}

// ---------------- 2-pass fp16 MFMA distance, z-split, per-z record with shortlist ----------
// x split into fp16 hi+lo (~22 bits); B single fp16, negated. acc init = x2/2 + c2/2
// -> acc_final = d2/2 >= 0; pack (score&~0x7F)|tag, u32 mins over this z-half (32 chunks).
// Record per (item,z): [m1(masked), k1, ns|fb<<8, pad, sv0, sk0, sv1, sk1]
__launch_bounds__(256, 2)
__global__ void k_dist(const float* __restrict__ xn, const unsigned short* __restrict__ panels,
                       const float* __restrict__ c2h, const float* __restrict__ x2h,
                       unsigned* __restrict__ recs) {
    __shared__ char smem[36864];   // 2 x 16KB staging; reduce scratch (33792B) overlaid after loop

    const int t    = threadIdx.x;
    const int lane = t & 63, wave = t >> 6;
    const int wm = wave >> 1, wn = wave & 1;
    const int col = lane & 15, quad = lane >> 4;
    const int q = blockIdx.y;
    const int z = blockIdx.z;
    const int row0 = blockIdx.x * 128;

    // A fragments (fp16 round-to-nearest split: x ~= hi + lo to ~22 bits)
    f16x8 ah[4][4], al[4][4];
    #pragma unroll
    for (int mt = 0; mt < 4; mt++) {
        #pragma unroll
        for (int kt = 0; kt < 4; kt++) {
            const float* ap = xn + (size_t)(row0 + wm * 64 + mt * 16 + col) * D_
                              + q * dd_ + kt * 32 + quad * 8;
            f32x4 v0 = *(const f32x4*)ap;
            f32x4 v1 = *(const f32x4*)(ap + 4);
            #pragma unroll
            for (int e = 0; e < 8; e++) {
                float xv = (e < 4) ? v0[e] : v1[e - 4];
                _Float16 h = (_Float16)xv;
                float r = xv - (float)h;
                ah[mt][kt][e] = h;
                al[mt][kt][e] = (_Float16)r;
            }
        }
    }

    // per-slot row halves of ||x_q||^2
    f32x4 x2v[4];
    #pragma unroll
    for (int mt = 0; mt < 4; mt++)
        #pragma unroll
        for (int r = 0; r < 4; r++)
            x2v[mt][r] = x2h[(size_t)(row0 + wm * 64 + mt * 16 + quad * 4 + r) * Q_ + q];

    unsigned m1[16], m2[16];
    #pragma unroll
    for (int i = 0; i < 16; i++) { m1[i] = 0xFFFFFFFFu; m2[i] = 0xFFFFFFFFu; }

    const size_t panq = (size_t)q * NCHUNK * 8192 + (size_t)z * NCH_L * 8192;
    const float* c2hq = c2h + q * K_ + z * (NCH_L * 64);

    // preload chunk 0 staging (16KB: 4 x 4KB global_load_lds_dwordx4)
    {
        const unsigned short* src = panels + panq;
        #pragma unroll
        for (int i = 0; i < 4; i++) {
            int boff = i * 4096 + t * 16;
            __builtin_amdgcn_global_load_lds((gas_p)((const char*)src + boff),
                                             (las_p)(smem + boff), 16, 0, 0);
        }
    }
    float ch0 = c2hq[wn * 32 + col];
    float ch1 = c2hq[wn * 32 + col + 16];

    for (int c = 0; c < NCH_L; c++) {
        __syncthreads();
        if (c + 1 < NCH_L) {
            const unsigned short* src = panels + panq + (size_t)(c + 1) * 8192;
            char* stage = smem + ((c + 1) & 1) * 16384;
            #pragma unroll
            for (int i = 0; i < 4; i++) {
                int boff = i * 4096 + t * 16;
                __builtin_amdgcn_global_load_lds((gas_p)((const char*)src + boff),
                                                 (las_p)(stage + boff), 16, 0, 0);
            }
        }
        float ch0n = 0.0f, ch1n = 0.0f;
        if (c + 1 < NCH_L) {
            ch0n = c2hq[(c + 1) * 64 + wn * 32 + col];
            ch1n = c2hq[(c + 1) * 64 + wn * 32 + col + 16];
        }
        const char* cbuf = smem + (c & 1) * 16384;

        f32x4 acc[4][2];
        #pragma unroll
        for (int mt = 0; mt < 4; mt++) {
            acc[mt][0] = x2v[mt] + ch0;   // d2/2 accumulator init
            acc[mt][1] = x2v[mt] + ch1;
        }

        #pragma unroll
        for (int kt = 0; kt < 4; kt++) {
            const int sw = ((quad + kt * 4) ^ col) * 16;
            const int a0 = (wn * 32 + col) * 256 + sw;        // codeword rows 0..15 of half 0
            const int a1 = a0 + 4096;                         // +16 rows (half 1)
            f16x8 b0 = *(const f16x8*)(cbuf + a0);
            f16x8 b1 = *(const f16x8*)(cbuf + a1);
            #pragma unroll
            for (int mt = 0; mt < 4; mt++) {
                acc[mt][0] = __builtin_amdgcn_mfma_f32_16x16x32_f16(ah[mt][kt], b0, acc[mt][0], 0, 0, 0);
                acc[mt][0] = __builtin_amdgcn_mfma_f32_16x16x32_f16(al[mt][kt], b0, acc[mt][0], 0, 0, 0);
                acc[mt][1] = __builtin_amdgcn_mfma_f32_16x16x32_f16(ah[mt][kt], b1, acc[mt][1], 0, 0, 0);
                acc[mt][1] = __builtin_amdgcn_mfma_f32_16x16x32_f16(al[mt][kt], b1, acc[mt][1], 0, 0, 0);
            }
        }

        const unsigned tg0 = (unsigned)((z * NCH_L + c) << 1), tg1 = tg0 | 1u;
        #pragma unroll
        for (int mt = 0; mt < 4; mt++) {
            #pragma unroll
            for (int r = 0; r < 4; r++) {
                const int sl = mt * 4 + r;
                unsigned p0 = (f2u(acc[mt][0][r]) & 0xFFFFFF80u) | tg0;
                unsigned p1 = (f2u(acc[mt][1][r]) & 0xFFFFFF80u) | tg1;
                unsigned pmin = umin_(p0, p1), pmax = umax_(p0, p1);
                m2[sl] = umin_(umin_(m2[sl], umax_(m1[sl], pmin)), pmax);  // min3 fusion
                m1[sl] = umin_(m1[sl], pmin);
            }
        }
        ch0 = ch0n; ch1 = ch1n;
    }

    // cross-lane merge per row (u32 domain; stride 33): min + shortlist + fallback detect
    __syncthreads();
    unsigned* rm1 = (unsigned*)smem;             // [128][33]
    unsigned* rm2 = (unsigned*)(smem + 16896);
    #pragma unroll
    for (int mt = 0; mt < 4; mt++) {
        #pragma unroll
        for (int r = 0; r < 4; r++) {
            int sl = mt * 4 + r;
            int row_l = wm * 64 + mt * 16 + quad * 4 + r;
            int e = wn * 16 + col;
            rm1[row_l * 33 + e] = m1[sl];
            rm2[row_l * 33 + e] = m2[sl];
        }
    }
    __syncthreads();
    if (t < 128) {
        unsigned b1 = 0xFFFFFFFFu;
        int be = 0;
        for (int e = 0; e < 32; e++) {
            unsigned v1 = rm1[t * 33 + e];
            if (v1 < b1) { b1 = v1; be = e; }
        }
        float f1  = u2f(b1 & 0xFFFFFF80u);
        float thr = f1 + TAU;
        int ns = 0, fb = 0;
        unsigned sv0 = 0xFFFFFFFFu, sk0 = 0, sv1 = 0xFFFFFFFFu, sk1 = 0;
        for (int e = 0; e < 32; e++) {
            unsigned v2m = rm2[t * 33 + e] & 0xFFFFFF80u;
            if (u2f(v2m) < thr) fb = 1;          // lane may hide a 3rd candidate in band
            if (e != be) {
                unsigned v1 = rm1[t * 33 + e];
                unsigned vm = v1 & 0xFFFFFF80u;
                if (u2f(vm) < thr) {
                    unsigned tg = v1 & 0x7Fu;
                    unsigned kk = ((tg >> 1) << 6) | (((unsigned)e >> 4) << 5)
                                | ((tg & 1u) << 4) | ((unsigned)e & 15u);
                    if (ns == 0)      { sv0 = vm; sk0 = kk; }
                    else if (ns == 1) { sv1 = vm; sk1 = kk; }
                    ns++;
                }
            }
        }
        if (ns > 2) fb = 1;
        unsigned tg1x = b1 & 0x7Fu;
        unsigned k1 = ((tg1x >> 1) << 6) | (((unsigned)be >> 4) << 5)
                    | ((tg1x & 1u) << 4) | ((unsigned)be & 15u);
        int item = (row0 + t) * Q_ + q;
        unsigned* rec = recs + ((size_t)item * 2 + z) * 8;
        rec[0] = b1 & 0xFFFFFF80u;
        rec[1] = k1;
        rec[2] = (unsigned)ns | ((unsigned)fb << 8);
        rec[3] = 0;
        rec[4] = sv0; rec[5] = sk0;
        rec[6] = sv1; rec[7] = sk1;
    }
}

// ---------------- merge z-records: winner idx, rescue routing ----------------
__global__ void k_merge(const unsigned* __restrict__ recs, int* __restrict__ idxi,
                        float* __restrict__ idxf, int* __restrict__ listF, int* __restrict__ cntF,
                        int* __restrict__ srl, int* __restrict__ cntS,
                        unsigned long long* __restrict__ resc) {
    int item = blockIdx.x * blockDim.x + threadIdx.x;
    if (item >= ROWS * Q_) return;
    const unsigned* ra = recs + (size_t)item * 16;
    const unsigned* rb = ra + 8;
    unsigned m1a = ra[0], m1b = rb[0];
    bool awin = m1a <= m1b;
    unsigned mw = awin ? m1a : m1b;
    unsigned kw = awin ? ra[1] : rb[1];
    unsigned ml = awin ? m1b : m1a;
    unsigned kl = awin ? rb[1] : ra[1];
    float thr = u2f(mw) + TAU;
    int fb = (int)(((ra[2] | rb[2]) >> 8) & 1u);

    bool q0 = u2f(ml) < thr;
    int nsa = (int)(ra[2] & 0xFFu), nsb = (int)(rb[2] & 0xFFu);
    bool qa0 = (nsa > 0) && (u2f(ra[4]) < thr);
    bool qa1 = (nsa > 1) && (u2f(ra[6]) < thr);
    bool qb0 = (nsb > 0) && (u2f(rb[4]) < thr);
    bool qb1 = (nsb > 1) && (u2f(rb[6]) < thr);
    int nr = (int)q0 + (int)qa0 + (int)qa1 + (int)qb0 + (int)qb1;

    idxi[item] = (int)kw;
    idxf[item] = (float)kw;
    if (fb) {
        resc[item] = 0xFFFFFFFFFFFFFFFFull;
        int p = atomicAdd(cntF, 1);
        listF[p] = item;
    } else if (nr > 0) {
        int p = atomicAdd(cntS, 1);
        int* e = srl + (size_t)p * 8;
        e[0] = item; e[1] = nr + 1; e[2] = (int)kw;
        int o = 3;
        if (q0)  e[o++] = (int)kl;
        if (qa0) e[o++] = (int)ra[5];
        if (qa1) e[o++] = (int)ra[7];
        if (qb0) e[o++] = (int)rb[5];
        if (qb1) e[o++] = (int)rb[7];
    }
}

// ---------------- exact fp32 rescue: shortlist blocks (<=6 cand) + full-scan fallback ----
__global__ void k_rescue(const float* __restrict__ xn, const float* __restrict__ cb,
                         const float* __restrict__ c2h, const int* __restrict__ listF,
                         const int* __restrict__ cntF, const int* __restrict__ srl,
                         const int* __restrict__ cntS,
                         unsigned long long* __restrict__ resc,
                         int* __restrict__ idxi, float* __restrict__ idxf) {
    __shared__ float xq[dd_];
    __shared__ unsigned long long kshare[8];
    const int t = threadIdx.x;
    if (blockIdx.x < 2048) {
        // ---- full-scan fallback: 8 blocks/item x 512 codewords ----
        const int n = *cntF;
        const int seg = blockIdx.x & 7;
        for (int ii = blockIdx.x >> 3; ii < n; ii += 256) {
            __syncthreads();
            int item = listF[ii];
            int rg = item >> 3, q = item & 7;
            if (t < dd_) xq[t] = xn[(size_t)rg * D_ + q * dd_ + t];
            __syncthreads();
            unsigned long long best = 0xFFFFFFFFFFFFFFFFull;
            #pragma unroll
            for (int i = 0; i < 2; i++) {
                int k = seg * 512 + i * 256 + t;
                const float* cp = cb + ((size_t)q * K_ + k) * dd_;
                float dot = 0.0f;
                #pragma unroll 8
                for (int d = 0; d < dd_; d += 4) {
                    f32x4 cv = *(const f32x4*)(cp + d);
                    dot = fmaf(cv.x, xq[d],     dot);
                    dot = fmaf(cv.y, xq[d + 1], dot);
                    dot = fmaf(cv.z, xq[d + 2], dot);
                    dot = fmaf(cv.w, xq[d + 3], dot);
                }
                float s = c2h[q * K_ + k] - dot;   // d2/2 - x2/2 (monotone in d2)
                unsigned long long key = ((unsigned long long)fflip(s) << 32) | (unsigned)k;
                best = best < key ? best : key;
            }
            #pragma unroll
            for (int o = 32; o > 0; o >>= 1) {
                unsigned long long other = shfl_xor_u64(best, o);
                best = best < other ? best : other;
            }
            if ((t & 63) == 0) kshare[t >> 6] = best;
            __syncthreads();
            if (t == 0) {
                unsigned long long b = kshare[0];
                b = b < kshare[1] ? b : kshare[1];
                b = b < kshare[2] ? b : kshare[2];
                b = b < kshare[3] ? b : kshare[3];
                atomicMin(&resc[item], b);
            }
        }
    } else {
        // ---- shortlist: 1 block/item, candidate per 32-lane group ----
        const int n = *cntS;
        for (int ii = (int)blockIdx.x - 2048; ii < n; ii += 2048) {
            __syncthreads();
            const int* e = srl + (size_t)ii * 8;
            int item = e[0], nc = e[1];
            int rg = item >> 3, q = item & 7;
            if (t < dd_) xq[t] = xn[(size_t)rg * D_ + q * dd_ + t];
            __syncthreads();
            int g = t >> 5, l = t & 31;
            unsigned long long key = 0xFFFFFFFFFFFFFFFFull;
            if (g < nc) {
                int k = e[2 + g];
                const float* cp = cb + ((size_t)q * K_ + k) * dd_ + l * 4;
                f32x4 cv = *(const f32x4*)cp;
                float dot = cv.x * xq[l * 4]     + cv.y * xq[l * 4 + 1]
                          + cv.z * xq[l * 4 + 2] + cv.w * xq[l * 4 + 3];
                dot += __shfl_xor(dot, 16, 64);
                dot += __shfl_xor(dot, 8, 64);
                dot += __shfl_xor(dot, 4, 64);
                dot += __shfl_xor(dot, 2, 64);
                dot += __shfl_xor(dot, 1, 64);
                float s = c2h[q * K_ + k] - dot;
                key = ((unsigned long long)fflip(s) << 32) | (unsigned)k;
            }
            if (l == 0) kshare[g] = key;
            __syncthreads();
            if (t == 0) {
                unsigned long long b = kshare[0];
                #pragma unroll
                for (int gg = 1; gg < 8; gg++) b = b < kshare[gg] ? b : kshare[gg];
                int k = (int)(unsigned)(b & 0xFFFFFFFFull);
                idxi[item] = k;
                idxf[item] = (float)k;
            }
        }
    }
}

// ---------------- decode full-scan winners into idxi/idxf ----------------
__global__ void k_fin(const int* __restrict__ listF, const int* __restrict__ cntF,
                      const unsigned long long* __restrict__ resc,
                      int* __restrict__ idxi, float* __restrict__ idxf) {
    const int n = *cntF;
    for (int i = blockIdx.x * blockDim.x + threadIdx.x; i < n; i += gridDim.x * blockDim.x) {
        int item = listF[i];
        int k = (int)(unsigned)(resc[item] & 0xFFFFFFFFull);
        idxi[item] = k;
        idxf[item] = (float)k;
    }
}

// ---------------- gather + output rmsnorm ----------------
__global__ void k_out(const float* __restrict__ cb, const int* __restrict__ idx_i,
                      const float* __restrict__ w, float* __restrict__ out) {
    int row = blockIdx.x;
    int t   = threadIdx.x;
    __shared__ int   sidx[Q_];
    __shared__ float acc[4];
    if (t < Q_) sidx[t] = idx_i[row * Q_ + t];
    __syncthreads();
    int col = t * 4;
    int q   = col >> 7;
    int dc  = col & 127;
    const float4 v = *(const float4*)(cb + ((size_t)q * K_ + sidx[q]) * dd_ + dc);
    float ss = v.x * v.x + v.y * v.y + v.z * v.z + v.w * v.w;
    #pragma unroll
    for (int o = 32; o > 0; o >>= 1) ss += __shfl_xor(ss, o, 64);
    if ((t & 63) == 0) acc[t >> 6] = ss;
    __syncthreads();
    float tot = (acc[0] + acc[1]) + (acc[2] + acc[3]);
    float sc  = 1.0f / sqrtf(tot * (1.0f / D_) + 1e-5f);
    const float4 wv = *(const float4*)(w + col);
    float4 o;
    o.x = v.x * sc * wv.x; o.y = v.y * sc * wv.y;
    o.z = v.z * sc * wv.z; o.w = v.w * sc * wv.w;
    *(float4*)(out + (size_t)row * D_ + col) = o;
}

extern "C" void kernel_launch(void* const* d_in, const int* in_sizes, int n_in,
                              void* d_out, int out_size, void* d_ws, size_t ws_size,
                              hipStream_t stream) {
    const float* x     = (const float*)d_in[0];
    const float* cb    = (const float*)d_in[1];
    const float* w_in  = (const float*)d_in[2];
    const float* w_out = (const float*)d_in[3];

    float* out  = (float*)d_out;                  // xn lives here between k_prep and k_out
    float* idxf = out + (size_t)ROWS * D_;

    // ws: panels 8MB | c2h 128KB | x2h 256KB | resc 512KB | idxi 256KB | listF 256KB
    //   | recs 4MB | srl 2MB | cntF,cntS
    unsigned short* panels = (unsigned short*)d_ws;
    float* c2h  = (float*)((char*)d_ws + (8u << 20));
    float* x2h  = c2h + Q_ * K_;
    unsigned long long* resc = (unsigned long long*)(x2h + (size_t)ROWS * Q_);
    int*   idxi = (int*)(resc + (size_t)ROWS * Q_);
    int*   listF = idxi + ROWS * Q_;
    unsigned* recs = (unsigned*)(listF + ROWS * Q_);
    int*   srl  = (int*)(recs + (size_t)ROWS * Q_ * 16);
    int*   cntF = srl + (size_t)ROWS * Q_ * 8;
    int*   cntS = cntF + 1;

    k_prep  <<<dim3(NCHUNK * Q_ + ROWS), 256, 0, stream>>>(cb, x, w_in, out, panels, c2h, x2h, cntF, cntS);
    k_dist  <<<dim3(ROWS / 128, Q_, 2),  256, 0, stream>>>(out, panels, c2h, x2h, recs);
    k_merge <<<dim3(ROWS * Q_ / 256),    256, 0, stream>>>(recs, idxi, idxf, listF, cntF, srl, cntS, resc);
    k_rescue<<<dim3(4096),               256, 0, stream>>>(out, cb, c2h, listF, cntF, srl, cntS, resc, idxi, idxf);
    k_fin   <<<dim3(64),                 256, 0, stream>>>(listF, cntF, resc, idxi, idxf);
    k_out   <<<dim3(ROWS),               256, 0, stream>>>(cb, idxi, w_out, out);
}